// Round 4
// baseline (205.649 us; speedup 1.0000x reference)
//
#include <hip/hip_runtime.h>
#include <cstdint>

#define EPSV 1e-5f
#define SM_SCALE 0.044194173824159216f

typedef unsigned short u16;
typedef __attribute__((ext_vector_type(8))) short short8;
typedef __attribute__((ext_vector_type(4))) float f32x4;
typedef __attribute__((ext_vector_type(4))) unsigned short us4;

__device__ __forceinline__ u16 f2bf(float f) {
  union { float f; uint32_t u; } v; v.f = f;
  return (u16)((v.u + 0x7FFFu + ((v.u >> 16) & 1u)) >> 16);
}

__device__ __forceinline__ void gload_lds16(const void* g, void* l) {
  __builtin_amdgcn_global_load_lds((const __attribute__((address_space(1))) void*)g,
                                   (__attribute__((address_space(3))) void*)l, 16, 0, 0);
}

__device__ __forceinline__ f32x4 mfma16(short8 a, short8 b, f32x4 c) {
  return __builtin_amdgcn_mfma_f32_16x16x32_bf16(a, b, c, 0, 0, 0);
}

// ---------- Fused GroupNorm (stats + apply in one pass via LDS) ----------
__global__ __launch_bounds__(256) void gn_fused_k(const float* __restrict__ x,
                                                  const float* __restrict__ gw,
                                                  const float* __restrict__ gb,
                                                  u16* __restrict__ xn) {
  __shared__ float xs[8192];
  __shared__ float ls[4], lss[4];
  const int bg = blockIdx.x;                     // 0..2047
  const int g = bg & 31;
  const float* p = x + (size_t)bg * 8192;
  float s = 0.f, ss = 0.f;
#pragma unroll
  for (int i = 0; i < 8; ++i) {
    const int idx = i * 1024 + threadIdx.x * 4;
    float4 v = *reinterpret_cast<const float4*>(p + idx);
    *reinterpret_cast<float4*>(xs + idx) = v;
    s += v.x + v.y + v.z + v.w;
    ss += v.x * v.x + v.y * v.y + v.z * v.z + v.w * v.w;
  }
  for (int off = 32; off; off >>= 1) { s += __shfl_xor(s, off); ss += __shfl_xor(ss, off); }
  const int w = threadIdx.x >> 6;
  if ((threadIdx.x & 63) == 0) { ls[w] = s; lss[w] = ss; }
  __syncthreads();
  s = ls[0] + ls[1] + ls[2] + ls[3];
  ss = lss[0] + lss[1] + lss[2] + lss[3];
  const float inv_n = 1.0f / 8192.f;
  const float mean = s * inv_n;
  const float rstd = rsqrtf(ss * inv_n - mean * mean + EPSV);
#pragma unroll
  for (int j = 0; j < 4; ++j) {
    const int idx = j * 2048 + threadIdx.x * 8;
    const int c = g * 16 + (idx >> 9);
    const float sc = gw[c] * rstd;
    const float sh = gb[c] - mean * sc;
    u16 o[8];
#pragma unroll
    for (int e = 0; e < 8; ++e) o[e] = f2bf(xs[idx + e] * sc + sh);
    *reinterpret_cast<uint4*>(xn + (size_t)bg * 8192 + idx) = *reinterpret_cast<const uint4*>(o);
  }
}

// ---------- fp32 -> bf16 cast for the 3 weight matrices ----------
__global__ __launch_bounds__(256) void cast3_k(const float* __restrict__ a,
                                               const float* __restrict__ b2,
                                               const float* __restrict__ c,
                                               u16* __restrict__ oa, u16* __restrict__ ob,
                                               u16* __restrict__ oc) {
  const int which = blockIdx.x >> 7;
  const float* in = which == 0 ? a : (which == 1 ? b2 : c);
  u16* out = which == 0 ? oa : (which == 1 ? ob : oc);
  size_t base = (((size_t)(blockIdx.x & 127)) * 256 + threadIdx.x) * 8;
  float4 v0 = *reinterpret_cast<const float4*>(in + base);
  float4 v1 = *reinterpret_cast<const float4*>(in + base + 4);
  u16 o[8];
  o[0] = f2bf(v0.x); o[1] = f2bf(v0.y); o[2] = f2bf(v0.z); o[3] = f2bf(v0.w);
  o[4] = f2bf(v1.x); o[5] = f2bf(v1.y); o[6] = f2bf(v1.z); o[7] = f2bf(v1.w);
  *reinterpret_cast<uint4*>(out + base) = *reinterpret_cast<const uint4*>(o);
}

// ---------- Fused QKV GEMM (2-phase prefetch) ----------
// Q[b,m,n] = xn.qw^T + qb ; K likewise ; V stored transposed: VT[b,n,m].
// 1024 blocks, XCD-bijective (batch b on XCD b>>3), 4 waves, 128x128 tile.
__global__ __launch_bounds__(256, 1) void qkv_fused_k(
    const u16* __restrict__ xn, const u16* __restrict__ qw,
    const u16* __restrict__ kw, const u16* __restrict__ vw,
    const float* __restrict__ qb, const float* __restrict__ kb,
    const float* __restrict__ vb,
    u16* __restrict__ Q, u16* __restrict__ K, u16* __restrict__ VT) {
  __shared__ u16 As[2][4096];
  __shared__ u16 Bq[2][4096], Bk[2][4096], Bv[2][4096];   // 64 KB total
  const int d = blockIdx.x;
  const int t = d >> 3;
  const int b = (d & 7) * 8 + (t >> 4);
  const int tile = t & 15;
  const int tm = (tile >> 2) * 128, tn = (tile & 3) * 128;
  const u16* Ab = xn + (size_t)b * 262144;
  const int tid = threadIdx.x, w = tid >> 6, lane = tid & 63;
  const int wr = (w >> 1) * 64, wc = (w & 1) * 64;
  const int srow = lane >> 2, scol = (lane & 3) * 8;
  f32x4 acc[3][4][4] = {};

#define QKV_STAGE(bb, k0)                                                      \
  {                                                                            \
    _Pragma("unroll")                                                          \
    for (int i = 0; i < 2; ++i) {                                              \
      const int ch = w + i * 4;                                                \
      const size_t ro = (size_t)(tn + ch * 16 + srow) * 512 + (k0) + scol;     \
      gload_lds16(Ab + (size_t)(tm + ch * 16 + srow) * 512 + (k0) + scol,      \
                  &As[bb][ch * 512]);                                          \
      gload_lds16(qw + ro, &Bq[bb][ch * 512]);                                 \
      gload_lds16(kw + ro, &Bk[bb][ch * 512]);                                 \
      gload_lds16(vw + ro, &Bv[bb][ch * 512]);                                 \
    }                                                                          \
  }

  QKV_STAGE(0, 0);
  __syncthreads();
  for (int ts = 0; ts < 16; ++ts) {
    const int cur = ts & 1;
    if (ts < 15) QKV_STAGE(cur ^ 1, (ts + 1) * 32);
    const int frow = lane & 15, fk = (lane >> 4) * 8;
    short8 af[4];
#pragma unroll
    for (int i = 0; i < 4; ++i)
      af[i] = *reinterpret_cast<const short8*>(&As[cur][(wr + i * 16 + frow) * 32 + fk]);
#pragma unroll
    for (int ni = 0; ni < 4; ++ni) {
      const int bo = (wc + ni * 16 + frow) * 32 + fk;
      short8 bq = *reinterpret_cast<const short8*>(&Bq[cur][bo]);
      short8 bk2 = *reinterpret_cast<const short8*>(&Bk[cur][bo]);
      short8 bv2 = *reinterpret_cast<const short8*>(&Bv[cur][bo]);
#pragma unroll
      for (int mi = 0; mi < 4; ++mi) {
        acc[0][mi][ni] = mfma16(af[mi], bq, acc[0][mi][ni]);
        acc[1][mi][ni] = mfma16(af[mi], bk2, acc[1][mi][ni]);
        acc[2][mi][ni] = mfma16(af[mi], bv2, acc[2][mi][ni]);
      }
    }
    __syncthreads();
  }
#undef QKV_STAGE

  const int col0 = lane & 15, row0 = (lane >> 4) * 4;
#pragma unroll
  for (int mi = 0; mi < 4; ++mi) {
#pragma unroll
    for (int ni = 0; ni < 4; ++ni) {
      const int gc = tn + wc + ni * 16 + col0;
      const int gr0 = tm + wr + mi * 16 + row0;
      const float qbv = qb[gc], kbv = kb[gc], vbv = vb[gc];
      us4 vt;
#pragma unroll
      for (int r = 0; r < 4; ++r) {
        const size_t o = (size_t)b * 262144 + (size_t)(gr0 + r) * 512 + gc;
        Q[o] = f2bf(acc[0][mi][ni][r] + qbv);
        K[o] = f2bf(acc[1][mi][ni][r] + kbv);
        vt[r] = f2bf(acc[2][mi][ni][r] + vbv);
      }
      // VT[b, gc, gr0..gr0+3]: 8B contiguous per lane
      *reinterpret_cast<us4*>(&VT[(size_t)b * 262144 + (size_t)gc * 512 + gr0]) = vt;
    }
  }
}

// ---------- scores + softmax -> P (bf16), 2-phase prefetch ----------
// QBLK=128, 8 waves; wave w owns 16 q-rows across all 512 keys (acc in regs).
__global__ __launch_bounds__(512, 2) void scores_softmax_k(const u16* __restrict__ Q,
                                                           const u16* __restrict__ K,
                                                           u16* __restrict__ P) {
  __shared__ u16 Qs[2][4096];     // 16 KB
  __shared__ u16 Ks[2][16384];    // 64 KB
  const int d = blockIdx.x;       // 0..255
  const int t = d >> 3;
  const int b = (d & 7) * 8 + (t >> 2);
  const int m0 = (t & 3) * 128;
  const u16* Qb = Q + (size_t)b * 262144 + (size_t)m0 * 512;
  const u16* Kb = K + (size_t)b * 262144;
  u16* Pb = P + (size_t)b * 262144;
  const int tid = threadIdx.x, w = tid >> 6, lane = tid & 63;
  const int srow = lane >> 2, scol = (lane & 3) * 8;
  f32x4 acc[32] = {};

#define SC_STAGE(bb, k0)                                                     \
  {                                                                          \
    _Pragma("unroll")                                                        \
    for (int i = 0; i < 4; ++i) {                                            \
      const int ch = w + i * 8;                                              \
      gload_lds16(Kb + (size_t)(ch * 16 + srow) * 512 + (k0) + scol,         \
                  &Ks[bb][ch * 512]);                                        \
    }                                                                        \
    gload_lds16(Qb + (size_t)(w * 16 + srow) * 512 + (k0) + scol,            \
                &Qs[bb][w * 512]);                                           \
  }

  SC_STAGE(0, 0);
  __syncthreads();
  for (int ts = 0; ts < 16; ++ts) {
    const int cur = ts & 1;
    if (ts < 15) SC_STAGE(cur ^ 1, (ts + 1) * 32);
    const int frow = lane & 15, fk = (lane >> 4) * 8;
    short8 aq = *reinterpret_cast<const short8*>(&Qs[cur][(w * 16 + frow) * 32 + fk]);
#pragma unroll
    for (int f = 0; f < 32; ++f) {
      short8 bk = *reinterpret_cast<const short8*>(&Ks[cur][(f * 16 + frow) * 32 + fk]);
      acc[f] = mfma16(aq, bk, acc[f]);
    }
    __syncthreads();
  }
#undef SC_STAGE

  float pm[4] = {-1e30f, -1e30f, -1e30f, -1e30f};
#pragma unroll
  for (int f = 0; f < 32; ++f)
#pragma unroll
    for (int r = 0; r < 4; ++r) {
      float v = acc[f][r] * SM_SCALE;
      acc[f][r] = v;
      pm[r] = fmaxf(pm[r], v);
    }
#pragma unroll
  for (int off = 1; off < 16; off <<= 1)
#pragma unroll
    for (int r = 0; r < 4; ++r) pm[r] = fmaxf(pm[r], __shfl_xor(pm[r], off));
  float ps[4] = {0.f, 0.f, 0.f, 0.f};
#pragma unroll
  for (int f = 0; f < 32; ++f)
#pragma unroll
    for (int r = 0; r < 4; ++r) {
      float e = __expf(acc[f][r] - pm[r]);
      acc[f][r] = e;
      ps[r] += e;
    }
#pragma unroll
  for (int off = 1; off < 16; off <<= 1)
#pragma unroll
    for (int r = 0; r < 4; ++r) ps[r] += __shfl_xor(ps[r], off);
  float rinv[4];
#pragma unroll
  for (int r = 0; r < 4; ++r) rinv[r] = 1.0f / ps[r];
#pragma unroll
  for (int f = 0; f < 32; ++f) {
    const int gcol = f * 16 + (lane & 15);
#pragma unroll
    for (int r = 0; r < 4; ++r) {
      const int grow = m0 + w * 16 + (lane >> 4) * 4 + r;
      Pb[(size_t)grow * 512 + gcol] = f2bf(acc[f][r] * rinv[r]);
    }
  }
}

// ---------- PV GEMM: out[m,n] = sum_k P[m,k]*VT[n,k]  (f32), 2-phase ----------
__global__ __launch_bounds__(256, 2) void pv_gemm_k(const u16* __restrict__ P,
                                                    const u16* __restrict__ VT,
                                                    float* __restrict__ out) {
  __shared__ u16 As[2][4096];
  __shared__ u16 Bs[2][4096];     // 32 KB
  const int d = blockIdx.x;
  const int t = d >> 3;
  const int b = (d & 7) * 8 + (t >> 4);
  const int tile = t & 15;
  const int tm = (tile >> 2) * 128, tn = (tile & 3) * 128;
  const u16* Ab = P + (size_t)b * 262144;
  const u16* Bb = VT + (size_t)b * 262144;
  const int tid = threadIdx.x, w = tid >> 6, lane = tid & 63;
  const int wr = (w >> 1) * 64, wc = (w & 1) * 64;
  const int srow = lane >> 2, scol = (lane & 3) * 8;
  f32x4 acc[4][4] = {};

#define PV_STAGE(bb, k0)                                                     \
  {                                                                          \
    _Pragma("unroll")                                                        \
    for (int i = 0; i < 2; ++i) {                                            \
      const int ch = w + i * 4;                                              \
      gload_lds16(Ab + (size_t)(tm + ch * 16 + srow) * 512 + (k0) + scol,    \
                  &As[bb][ch * 512]);                                        \
      gload_lds16(Bb + (size_t)(tn + ch * 16 + srow) * 512 + (k0) + scol,    \
                  &Bs[bb][ch * 512]);                                        \
    }                                                                        \
  }

  PV_STAGE(0, 0);
  __syncthreads();
  for (int ts = 0; ts < 16; ++ts) {
    const int cur = ts & 1;
    if (ts < 15) PV_STAGE(cur ^ 1, (ts + 1) * 32);
    const int frow = lane & 15, fk = (lane >> 4) * 8;
    short8 af[4], bf[4];
#pragma unroll
    for (int i = 0; i < 4; ++i) {
      af[i] = *reinterpret_cast<const short8*>(&As[cur][(wr + i * 16 + frow) * 32 + fk]);
      bf[i] = *reinterpret_cast<const short8*>(&Bs[cur][(wc + i * 16 + frow) * 32 + fk]);
    }
#pragma unroll
    for (int mi = 0; mi < 4; ++mi)
#pragma unroll
      for (int ni = 0; ni < 4; ++ni)
        acc[mi][ni] = mfma16(af[mi], bf[ni], acc[mi][ni]);
    __syncthreads();
  }
#undef PV_STAGE

  const int col0 = lane & 15, row0 = (lane >> 4) * 4;
#pragma unroll
  for (int mi = 0; mi < 4; ++mi)
#pragma unroll
    for (int ni = 0; ni < 4; ++ni) {
      const int gc = tn + wc + ni * 16 + col0;
#pragma unroll
      for (int r = 0; r < 4; ++r) {
        const int gr = tm + wr + mi * 16 + row0 + r;
        out[(size_t)b * 262144 + (size_t)gr * 512 + gc] = acc[mi][ni][r];
      }
    }
}

extern "C" void kernel_launch(void* const* d_in, const int* in_sizes, int n_in,
                              void* d_out, int out_size, void* d_ws, size_t ws_size,
                              hipStream_t stream) {
  const float* x = (const float*)d_in[0];
  const float* qw = (const float*)d_in[1];
  const float* qb = (const float*)d_in[2];
  const float* kw = (const float*)d_in[3];
  const float* kb = (const float*)d_in[4];
  const float* vw = (const float*)d_in[5];
  const float* vb = (const float*)d_in[6];
  const float* gnw = (const float*)d_in[7];
  const float* gnb = (const float*)d_in[8];

  char* ws = (char*)d_ws;
  u16* qwb = (u16*)(ws);
  u16* kwb = (u16*)(ws + 524288);
  u16* vwb = (u16*)(ws + 2 * 524288);
  u16* xn = (u16*)(ws + 4 * 524288);
  u16* Qb = xn + 16777216;
  u16* Kb = Qb + 16777216;
  u16* VT = Kb + 16777216;
  u16* P = xn;                       // xn dead after QKV
  float* out = (float*)d_out;

  gn_fused_k<<<dim3(2048), dim3(256), 0, stream>>>(x, gnw, gnb, xn);
  cast3_k<<<dim3(384), dim3(256), 0, stream>>>(qw, kw, vw, qwb, kwb, vwb);
  qkv_fused_k<<<dim3(1024), dim3(256), 0, stream>>>(xn, qwb, kwb, vwb, qb, kb, vb, Qb, Kb, VT);
  scores_softmax_k<<<dim3(256), dim3(512), 0, stream>>>(Qb, Kb, P);
  pv_gemm_k<<<dim3(1024), dim3(256), 0, stream>>>(P, VT, out);
}

// Round 5
// 169.615 us; speedup vs baseline: 1.2124x; 1.2124x over previous
//
#include <hip/hip_runtime.h>
#include <cstdint>

#define EPSV 1e-5f
#define SM_SCALE 0.044194173824159216f

typedef unsigned short u16;
typedef __attribute__((ext_vector_type(8))) short short8;
typedef __attribute__((ext_vector_type(4))) float f32x4;
typedef __attribute__((ext_vector_type(4))) unsigned short us4;

__device__ __forceinline__ u16 f2bf(float f) {
  union { float f; uint32_t u; } v; v.f = f;
  return (u16)((v.u + 0x7FFFu + ((v.u >> 16) & 1u)) >> 16);
}

__device__ __forceinline__ void gload_lds16(const void* g, void* l) {
  __builtin_amdgcn_global_load_lds((const __attribute__((address_space(1))) void*)g,
                                   (__attribute__((address_space(3))) void*)l, 16, 0, 0);
}

__device__ __forceinline__ f32x4 mfma16(short8 a, short8 b, f32x4 c) {
  return __builtin_amdgcn_mfma_f32_16x16x32_bf16(a, b, c, 0, 0, 0);
}

// Counted-vmcnt barrier pair (T3+T4 minimum recipe): keep newest stage's loads
// in flight across the barrier; only the tail iteration drains to 0.
#define WAIT_ENTER(N, is_tail)                                      \
  if (is_tail) { asm volatile("s_waitcnt vmcnt(0)" ::: "memory"); } \
  else         { asm volatile("s_waitcnt vmcnt(" #N ")" ::: "memory"); } \
  __builtin_amdgcn_s_barrier();                                     \
  asm volatile("" ::: "memory");

#define WAIT_EXIT()                                                 \
  asm volatile("s_waitcnt lgkmcnt(0)" ::: "memory");                \
  __builtin_amdgcn_s_barrier();                                     \
  asm volatile("" ::: "memory");

// ---------- Fused GroupNorm (stats + apply in one pass via LDS) ----------
__global__ __launch_bounds__(256) void gn_fused_k(const float* __restrict__ x,
                                                  const float* __restrict__ gw,
                                                  const float* __restrict__ gb,
                                                  u16* __restrict__ xn) {
  __shared__ float xs[8192];
  __shared__ float ls[4], lss[4];
  const int bg = blockIdx.x;                     // 0..2047
  const int g = bg & 31;
  const float* p = x + (size_t)bg * 8192;
  float s = 0.f, ss = 0.f;
#pragma unroll
  for (int i = 0; i < 8; ++i) {
    const int idx = i * 1024 + threadIdx.x * 4;
    float4 v = *reinterpret_cast<const float4*>(p + idx);
    *reinterpret_cast<float4*>(xs + idx) = v;
    s += v.x + v.y + v.z + v.w;
    ss += v.x * v.x + v.y * v.y + v.z * v.z + v.w * v.w;
  }
  for (int off = 32; off; off >>= 1) { s += __shfl_xor(s, off); ss += __shfl_xor(ss, off); }
  const int w = threadIdx.x >> 6;
  if ((threadIdx.x & 63) == 0) { ls[w] = s; lss[w] = ss; }
  __syncthreads();
  s = ls[0] + ls[1] + ls[2] + ls[3];
  ss = lss[0] + lss[1] + lss[2] + lss[3];
  const float inv_n = 1.0f / 8192.f;
  const float mean = s * inv_n;
  const float rstd = rsqrtf(ss * inv_n - mean * mean + EPSV);
#pragma unroll
  for (int j = 0; j < 4; ++j) {
    const int idx = j * 2048 + threadIdx.x * 8;
    const int c = g * 16 + (idx >> 9);
    const float sc = gw[c] * rstd;
    const float sh = gb[c] - mean * sc;
    u16 o[8];
#pragma unroll
    for (int e = 0; e < 8; ++e) o[e] = f2bf(xs[idx + e] * sc + sh);
    *reinterpret_cast<uint4*>(xn + (size_t)bg * 8192 + idx) = *reinterpret_cast<const uint4*>(o);
  }
}

// ---------- fp32 -> bf16 cast for the 3 weight matrices ----------
__global__ __launch_bounds__(256) void cast3_k(const float* __restrict__ a,
                                               const float* __restrict__ b2,
                                               const float* __restrict__ c,
                                               u16* __restrict__ oa, u16* __restrict__ ob,
                                               u16* __restrict__ oc) {
  const int which = blockIdx.x >> 7;
  const float* in = which == 0 ? a : (which == 1 ? b2 : c);
  u16* out = which == 0 ? oa : (which == 1 ? ob : oc);
  size_t base = (((size_t)(blockIdx.x & 127)) * 256 + threadIdx.x) * 8;
  float4 v0 = *reinterpret_cast<const float4*>(in + base);
  float4 v1 = *reinterpret_cast<const float4*>(in + base + 4);
  u16 o[8];
  o[0] = f2bf(v0.x); o[1] = f2bf(v0.y); o[2] = f2bf(v0.z); o[3] = f2bf(v0.w);
  o[4] = f2bf(v1.x); o[5] = f2bf(v1.y); o[6] = f2bf(v1.z); o[7] = f2bf(v1.w);
  *reinterpret_cast<uint4*>(out + base) = *reinterpret_cast<const uint4*>(o);
}

// ---------- Fused QKV GEMM (2-deep counted-vmcnt pipeline) ----------
// Q[b,m,n] = xn.qw^T + qb ; K likewise ; V stored transposed: VT[b,n,m].
__global__ __launch_bounds__(256, 1) void qkv_fused_k(
    const u16* __restrict__ xn, const u16* __restrict__ qw,
    const u16* __restrict__ kw, const u16* __restrict__ vw,
    const float* __restrict__ qb, const float* __restrict__ kb,
    const float* __restrict__ vb,
    u16* __restrict__ Q, u16* __restrict__ K, u16* __restrict__ VT) {
  __shared__ u16 As[2][4096];
  __shared__ u16 Bq[2][4096], Bk[2][4096], Bv[2][4096];   // 64 KB total
  const int d = blockIdx.x;
  const int t = d >> 3;
  const int b = (d & 7) * 8 + (t >> 4);
  const int tile = t & 15;
  const int tm = (tile >> 2) * 128, tn = (tile & 3) * 128;
  const u16* Ab = xn + (size_t)b * 262144;
  const int tid = threadIdx.x, w = tid >> 6, lane = tid & 63;
  const int wr = (w >> 1) * 64, wc = (w & 1) * 64;
  const int srow = lane >> 2, scol = (lane & 3) * 8;
  f32x4 acc[3][4][4] = {};

#define QKV_STAGE(bb, k0)                                                      \
  {                                                                            \
    _Pragma("unroll")                                                          \
    for (int i = 0; i < 2; ++i) {                                              \
      const int ch = w + i * 4;                                                \
      const size_t ro = (size_t)(tn + ch * 16 + srow) * 512 + (k0) + scol;     \
      gload_lds16(Ab + (size_t)(tm + ch * 16 + srow) * 512 + (k0) + scol,      \
                  &As[bb][ch * 512]);                                          \
      gload_lds16(qw + ro, &Bq[bb][ch * 512]);                                 \
      gload_lds16(kw + ro, &Bk[bb][ch * 512]);                                 \
      gload_lds16(vw + ro, &Bv[bb][ch * 512]);                                 \
    }                                                                          \
  }

  QKV_STAGE(0, 0);      // 8 loads/thread in flight
  QKV_STAGE(1, 32);     // 16 in flight
  for (int ts = 0; ts < 16; ++ts) {
    const int cur = ts & 1;
    WAIT_ENTER(8, ts == 15);          // buf[cur] ready; newest 8 stay in flight
    const int frow = lane & 15, fk = (lane >> 4) * 8;
    short8 af[4];
#pragma unroll
    for (int i = 0; i < 4; ++i)
      af[i] = *reinterpret_cast<const short8*>(&As[cur][(wr + i * 16 + frow) * 32 + fk]);
#pragma unroll
    for (int ni = 0; ni < 4; ++ni) {
      const int bo = (wc + ni * 16 + frow) * 32 + fk;
      short8 bq = *reinterpret_cast<const short8*>(&Bq[cur][bo]);
      short8 bk2 = *reinterpret_cast<const short8*>(&Bk[cur][bo]);
      short8 bv2 = *reinterpret_cast<const short8*>(&Bv[cur][bo]);
#pragma unroll
      for (int mi = 0; mi < 4; ++mi) {
        acc[0][mi][ni] = mfma16(af[mi], bq, acc[0][mi][ni]);
        acc[1][mi][ni] = mfma16(af[mi], bk2, acc[1][mi][ni]);
        acc[2][mi][ni] = mfma16(af[mi], bv2, acc[2][mi][ni]);
      }
    }
    WAIT_EXIT();                      // all waves done reading buf[cur]
    if (ts < 14) QKV_STAGE(cur, (ts + 2) * 32);
  }
#undef QKV_STAGE

  const int col0 = lane & 15, row0 = (lane >> 4) * 4;
#pragma unroll
  for (int mi = 0; mi < 4; ++mi) {
#pragma unroll
    for (int ni = 0; ni < 4; ++ni) {
      const int gc = tn + wc + ni * 16 + col0;
      const int gr0 = tm + wr + mi * 16 + row0;
      const float qbv = qb[gc], kbv = kb[gc], vbv = vb[gc];
      us4 vt;
#pragma unroll
      for (int r = 0; r < 4; ++r) {
        const size_t o = (size_t)b * 262144 + (size_t)(gr0 + r) * 512 + gc;
        Q[o] = f2bf(acc[0][mi][ni][r] + qbv);
        K[o] = f2bf(acc[1][mi][ni][r] + kbv);
        vt[r] = f2bf(acc[2][mi][ni][r] + vbv);
      }
      *reinterpret_cast<us4*>(&VT[(size_t)b * 262144 + (size_t)gc * 512 + gr0]) = vt;
    }
  }
}

// ---------- scores + softmax -> P (bf16), 2-deep counted-vmcnt ----------
__global__ __launch_bounds__(512, 2) void scores_softmax_k(const u16* __restrict__ Q,
                                                           const u16* __restrict__ K,
                                                           u16* __restrict__ P) {
  __shared__ u16 Qs[2][4096];     // 16 KB
  __shared__ u16 Ks[2][16384];    // 64 KB
  const int d = blockIdx.x;       // 0..255
  const int t = d >> 3;
  const int b = (d & 7) * 8 + (t >> 2);
  const int m0 = (t & 3) * 128;
  const u16* Qb = Q + (size_t)b * 262144 + (size_t)m0 * 512;
  const u16* Kb = K + (size_t)b * 262144;
  u16* Pb = P + (size_t)b * 262144;
  const int tid = threadIdx.x, w = tid >> 6, lane = tid & 63;
  const int srow = lane >> 2, scol = (lane & 3) * 8;
  f32x4 acc[32] = {};

#define SC_STAGE(bb, k0)                                                     \
  {                                                                          \
    _Pragma("unroll")                                                        \
    for (int i = 0; i < 4; ++i) {                                            \
      const int ch = w + i * 8;                                              \
      gload_lds16(Kb + (size_t)(ch * 16 + srow) * 512 + (k0) + scol,         \
                  &Ks[bb][ch * 512]);                                        \
    }                                                                        \
    gload_lds16(Qb + (size_t)(w * 16 + srow) * 512 + (k0) + scol,            \
                &Qs[bb][w * 512]);                                           \
  }

  SC_STAGE(0, 0);       // 5 loads/thread
  SC_STAGE(1, 32);      // 10 in flight
  for (int ts = 0; ts < 16; ++ts) {
    const int cur = ts & 1;
    WAIT_ENTER(5, ts == 15);
    const int frow = lane & 15, fk = (lane >> 4) * 8;
    short8 aq = *reinterpret_cast<const short8*>(&Qs[cur][(w * 16 + frow) * 32 + fk]);
#pragma unroll
    for (int f = 0; f < 32; ++f) {
      short8 bk = *reinterpret_cast<const short8*>(&Ks[cur][(f * 16 + frow) * 32 + fk]);
      acc[f] = mfma16(aq, bk, acc[f]);
    }
    WAIT_EXIT();
    if (ts < 14) SC_STAGE(cur, (ts + 2) * 32);
  }
#undef SC_STAGE

  float pm[4] = {-1e30f, -1e30f, -1e30f, -1e30f};
#pragma unroll
  for (int f = 0; f < 32; ++f)
#pragma unroll
    for (int r = 0; r < 4; ++r) {
      float v = acc[f][r] * SM_SCALE;
      acc[f][r] = v;
      pm[r] = fmaxf(pm[r], v);
    }
#pragma unroll
  for (int off = 1; off < 16; off <<= 1)
#pragma unroll
    for (int r = 0; r < 4; ++r) pm[r] = fmaxf(pm[r], __shfl_xor(pm[r], off));
  float ps[4] = {0.f, 0.f, 0.f, 0.f};
#pragma unroll
  for (int f = 0; f < 32; ++f)
#pragma unroll
    for (int r = 0; r < 4; ++r) {
      float e = __expf(acc[f][r] - pm[r]);
      acc[f][r] = e;
      ps[r] += e;
    }
#pragma unroll
  for (int off = 1; off < 16; off <<= 1)
#pragma unroll
    for (int r = 0; r < 4; ++r) ps[r] += __shfl_xor(ps[r], off);
  float rinv[4];
#pragma unroll
  for (int r = 0; r < 4; ++r) rinv[r] = 1.0f / ps[r];
#pragma unroll
  for (int f = 0; f < 32; ++f) {
    const int gcol = f * 16 + (lane & 15);
#pragma unroll
    for (int r = 0; r < 4; ++r) {
      const int grow = m0 + w * 16 + (lane >> 4) * 4 + r;
      Pb[(size_t)grow * 512 + gcol] = f2bf(acc[f][r] * rinv[r]);
    }
  }
}

// ---------- PV GEMM: out[m,n] = sum_k P[m,k]*VT[n,k] (f32), 2-deep counted ----------
__global__ __launch_bounds__(256, 2) void pv_gemm_k(const u16* __restrict__ P,
                                                    const u16* __restrict__ VT,
                                                    float* __restrict__ out) {
  __shared__ u16 As[2][4096];
  __shared__ u16 Bs[2][4096];     // 32 KB
  const int d = blockIdx.x;
  const int t = d >> 3;
  const int b = (d & 7) * 8 + (t >> 4);
  const int tile = t & 15;
  const int tm = (tile >> 2) * 128, tn = (tile & 3) * 128;
  const u16* Ab = P + (size_t)b * 262144;
  const u16* Bb = VT + (size_t)b * 262144;
  const int tid = threadIdx.x, w = tid >> 6, lane = tid & 63;
  const int wr = (w >> 1) * 64, wc = (w & 1) * 64;
  const int srow = lane >> 2, scol = (lane & 3) * 8;
  f32x4 acc[4][4] = {};

#define PV_STAGE(bb, k0)                                                     \
  {                                                                          \
    _Pragma("unroll")                                                        \
    for (int i = 0; i < 2; ++i) {                                            \
      const int ch = w + i * 4;                                              \
      gload_lds16(Ab + (size_t)(tm + ch * 16 + srow) * 512 + (k0) + scol,    \
                  &As[bb][ch * 512]);                                        \
      gload_lds16(Bb + (size_t)(tn + ch * 16 + srow) * 512 + (k0) + scol,    \
                  &Bs[bb][ch * 512]);                                        \
    }                                                                        \
  }

  PV_STAGE(0, 0);       // 4 loads/thread
  PV_STAGE(1, 32);      // 8 in flight
  for (int ts = 0; ts < 16; ++ts) {
    const int cur = ts & 1;
    WAIT_ENTER(4, ts == 15);
    const int frow = lane & 15, fk = (lane >> 4) * 8;
    short8 af[4], bf[4];
#pragma unroll
    for (int i = 0; i < 4; ++i) {
      af[i] = *reinterpret_cast<const short8*>(&As[cur][(wr + i * 16 + frow) * 32 + fk]);
      bf[i] = *reinterpret_cast<const short8*>(&Bs[cur][(wc + i * 16 + frow) * 32 + fk]);
    }
#pragma unroll
    for (int mi = 0; mi < 4; ++mi)
#pragma unroll
      for (int ni = 0; ni < 4; ++ni)
        acc[mi][ni] = mfma16(af[mi], bf[ni], acc[mi][ni]);
    WAIT_EXIT();
    if (ts < 14) PV_STAGE(cur, (ts + 2) * 32);
  }
#undef PV_STAGE

  const int col0 = lane & 15, row0 = (lane >> 4) * 4;
#pragma unroll
  for (int mi = 0; mi < 4; ++mi)
#pragma unroll
    for (int ni = 0; ni < 4; ++ni) {
      const int gc = tn + wc + ni * 16 + col0;
#pragma unroll
      for (int r = 0; r < 4; ++r) {
        const int gr = tm + wr + mi * 16 + row0 + r;
        out[(size_t)b * 262144 + (size_t)gr * 512 + gc] = acc[mi][ni][r];
      }
    }
}

extern "C" void kernel_launch(void* const* d_in, const int* in_sizes, int n_in,
                              void* d_out, int out_size, void* d_ws, size_t ws_size,
                              hipStream_t stream) {
  const float* x = (const float*)d_in[0];
  const float* qw = (const float*)d_in[1];
  const float* qb = (const float*)d_in[2];
  const float* kw = (const float*)d_in[3];
  const float* kb = (const float*)d_in[4];
  const float* vw = (const float*)d_in[5];
  const float* vb = (const float*)d_in[6];
  const float* gnw = (const float*)d_in[7];
  const float* gnb = (const float*)d_in[8];

  char* ws = (char*)d_ws;
  u16* qwb = (u16*)(ws);
  u16* kwb = (u16*)(ws + 524288);
  u16* vwb = (u16*)(ws + 2 * 524288);
  u16* xn = (u16*)(ws + 4 * 524288);
  u16* Qb = xn + 16777216;
  u16* Kb = Qb + 16777216;
  u16* VT = Kb + 16777216;
  u16* P = xn;                       // xn dead after QKV
  float* out = (float*)d_out;

  gn_fused_k<<<dim3(2048), dim3(256), 0, stream>>>(x, gnw, gnb, xn);
  cast3_k<<<dim3(384), dim3(256), 0, stream>>>(qw, kw, vw, qwb, kwb, vwb);
  qkv_fused_k<<<dim3(1024), dim3(256), 0, stream>>>(xn, qwb, kwb, vwb, qb, kb, vb, Qb, Kb, VT);
  scores_softmax_k<<<dim3(256), dim3(512), 0, stream>>>(Qb, Kb, P);
  pv_gemm_k<<<dim3(1024), dim3(256), 0, stream>>>(P, VT, out);
}